// Round 12
// baseline (62.478 us; speedup 1.0000x reference)
//
#include <hip/hip_runtime.h>

#define NEG_SLOPE 0.2f
#define EPS 1e-6f

// x: [B=4, C=64, V=3, N=32768] f32, W: [64,64] f32, out like x
// d[o,v,n] = sum_i W[o,i]*x[i,v,n]; out = dot>=0 ? x : x - 0.8*(dot/(dnsq+eps))*d
// Barrier-free, zero-LDS: each wave loads its own MFMA B-fragments (x) straight
// from global (L1/L2 absorb the small re-read), computes d = W·x via bf16 MFMA
// with hi/lo 3-product split, re-reads exact fp32 x from L2 for the epilogue.
// No __syncthreads anywhere; occupancy capped only by VGPR.

#define C_CH 64
#define V_DIM 3
#define N_FULL 32768
#define THREADS 256

typedef __attribute__((ext_vector_type(8))) short bf16x8;
typedef __attribute__((ext_vector_type(4))) float f32x4;

__device__ __forceinline__ ushort f2bf(float f) {
    union { float f; unsigned u; } v; v.f = f;
    unsigned r = v.u + 0x7FFFu + ((v.u >> 16) & 1u);  // RNE
    return (ushort)(r >> 16);
}
__device__ __forceinline__ float bf2f(ushort s) {
    union { unsigned u; float f; } v; v.u = ((unsigned)s) << 16; return v.f;
}
__device__ __forceinline__ unsigned f2u(float f) {
    union { float f; unsigned u; } v; v.f = f; return v.u;
}
__device__ __forceinline__ float u2f(unsigned u) {
    union { unsigned u; float f; } v; v.u = u; return v.f;
}

// ---- pre-kernel: split W fp32 -> Whi/Wlo bf16 (8 KB each), RNE both
__global__ void w_split_kernel(const float* __restrict__ W,
                               ushort* __restrict__ whi, ushort* __restrict__ wlo) {
    int i = blockIdx.x * 256 + threadIdx.x;
    if (i < C_CH * C_CH) {
        float w = W[i];
        ushort h = f2bf(w);
        whi[i] = h;
        wlo[i] = f2bf(w - bf2f(h));
    }
}

template<bool USE_WS>
__global__ __launch_bounds__(THREADS, 6)
void vn_nolds(const float* __restrict__ x,
              const float* __restrict__ Wf,
              const ushort* __restrict__ whi, const ushort* __restrict__ wlo,
              float* __restrict__ out) {
    const int t    = threadIdx.x;
    const int tile = blockIdx.x;
    const int b    = tile >> 10;            // 1024 tiles per batch
    const int n0   = (tile & 1023) << 5;    // *32

    const float* xb = x + (size_t)b * (C_CH * V_DIM * N_FULL) + n0;

    const int lane = t & 63;
    const int w    = t >> 6;   // 0..3
    const int wo   = w >> 1;   // o-half -> 32 channels
    const int wn   = w & 1;    // n-half -> 16 cols
    const int l4   = lane & 15;
    const int hi   = lane >> 4;
    const int n    = wn * 16 + l4;

    // ---- A fragments (W): row o = wo*32+m*16+l4, k = kh*32+hi*8+j
    bf16x8 Ah[2][2], Al[2][2];
    if (USE_WS) {
        #pragma unroll
        for (int m = 0; m < 2; ++m)
            #pragma unroll
            for (int kh = 0; kh < 2; ++kh) {
                size_t off = (size_t)(wo * 32 + m * 16 + l4) * C_CH + kh * 32 + hi * 8;
                Ah[m][kh] = *(const bf16x8*)(whi + off);
                Al[m][kh] = *(const bf16x8*)(wlo + off);
            }
    } else {
        #pragma unroll
        for (int m = 0; m < 2; ++m)
            #pragma unroll
            for (int kh = 0; kh < 2; ++kh) {
                const float* wp = Wf + (size_t)(wo * 32 + m * 16 + l4) * C_CH + kh * 32 + hi * 8;
                float4 wa = *(const float4*)wp;
                float4 wb = *(const float4*)(wp + 4);
                float wf[8] = {wa.x, wa.y, wa.z, wa.w, wb.x, wb.y, wb.z, wb.w};
                bf16x8 h, l;
                #pragma unroll
                for (int j = 0; j < 8; ++j) {
                    ushort hb = f2bf(wf[j]);
                    h[j] = (short)hb;
                    l[j] = (short)f2bf(wf[j] - bf2f(hb));
                }
                Ah[m][kh] = h; Al[m][kh] = l;
            }
    }

    f32x4 acc[2][3];
    #pragma unroll
    for (int m = 0; m < 2; ++m)
        #pragma unroll
        for (int v = 0; v < 3; ++v)
            acc[m][v] = (f32x4){0.f, 0.f, 0.f, 0.f};

    // ---- B-frags straight from global: B[k=hi*8+j][col=l4] =
    //      x[i=kh*32+hi*8+j][v][n0+n];  lane addr = bb + (kh*96+3j+v)*N
    const float* bb = xb + (size_t)(hi * 8) * (V_DIM * N_FULL) + n;
    #pragma unroll
    for (int v = 0; v < 3; ++v) {
        #pragma unroll
        for (int kh = 0; kh < 2; ++kh) {
            float f[8];
            #pragma unroll
            for (int j = 0; j < 8; ++j)
                f[j] = bb[(size_t)(kh * 96 + 3 * j + v) * N_FULL];
            // hi = truncated bf16 (pure perm), lo = trunc(f - hi)
            union { bf16x8 v8; unsigned d[4]; } BH, BL;
            unsigned rl[8];
            #pragma unroll
            for (int j = 0; j < 8; ++j)
                rl[j] = f2u(f[j] - u2f(f2u(f[j]) & 0xffff0000u));
            #pragma unroll
            for (int q = 0; q < 4; ++q) {
                BH.d[q] = __builtin_amdgcn_perm(f2u(f[2 * q + 1]), f2u(f[2 * q]), 0x07060302u);
                BL.d[q] = __builtin_amdgcn_perm(rl[2 * q + 1], rl[2 * q], 0x07060302u);
            }
            #pragma unroll
            for (int m = 0; m < 2; ++m) {
                acc[m][v] = __builtin_amdgcn_mfma_f32_16x16x32_bf16(Ah[m][kh], BH.v8, acc[m][v], 0, 0, 0);
                acc[m][v] = __builtin_amdgcn_mfma_f32_16x16x32_bf16(Ah[m][kh], BL.v8, acc[m][v], 0, 0, 0);
                acc[m][v] = __builtin_amdgcn_mfma_f32_16x16x32_bf16(Al[m][kh], BH.v8, acc[m][v], 0, 0, 0);
            }
        }
    }

    // ---- epilogue: C/D col=l4 (n), row=hi*4+rr (o within 16); exact fp32 x
    // re-read from global (L2-hot: this wave loaded these lines in the B-phase)
    float* ob = out + (size_t)b * (C_CH * V_DIM * N_FULL) + n0 + n;
    #pragma unroll
    for (int m = 0; m < 2; ++m) {
        #pragma unroll
        for (int rr = 0; rr < 4; ++rr) {
            const int o = wo * 32 + m * 16 + hi * 4 + rr;
            const float* ep = xb + (size_t)(o * 3) * N_FULL + n;
            float xv[3], dv[3];
            #pragma unroll
            for (int v = 0; v < 3; ++v) {
                xv[v] = ep[(size_t)v * N_FULL];
                dv[v] = acc[m][v][rr];
            }
            float dot  = xv[0] * dv[0] + xv[1] * dv[1] + xv[2] * dv[2];
            float dnsq = dv[0] * dv[0] + dv[1] * dv[1] + dv[2] * dv[2];
            float f = (1.0f - NEG_SLOPE) * dot * __builtin_amdgcn_rcpf(dnsq + EPS);
            f = (dot >= 0.f) ? 0.f : f;
            float o0 = fmaf(-f, dv[0], xv[0]);
            float o1 = fmaf(-f, dv[1], xv[1]);
            float o2 = fmaf(-f, dv[2], xv[2]);
            float* op = ob + (size_t)o * (V_DIM * N_FULL);
            op[0 * N_FULL] = o0;
            op[1 * N_FULL] = o1;
            op[2 * N_FULL] = o2;
        }
    }
}

extern "C" void kernel_launch(void* const* d_in, const int* in_sizes, int n_in,
                              void* d_out, int out_size, void* d_ws, size_t ws_size,
                              hipStream_t stream) {
    const float* x = (const float*)d_in[0];
    const float* W = (const float*)d_in[1];
    float* out = (float*)d_out;

    const int B = 4;
    const int blocks = B * (N_FULL / 32);  // 4096

    if (ws_size >= 2u * C_CH * C_CH * sizeof(ushort)) {
        ushort* whi = (ushort*)d_ws;
        ushort* wlo = whi + C_CH * C_CH;
        w_split_kernel<<<(C_CH * C_CH + 255) / 256, 256, 0, stream>>>(W, whi, wlo);
        vn_nolds<true><<<blocks, THREADS, 0, stream>>>(x, W, whi, wlo, out);
    } else {
        vn_nolds<false><<<blocks, THREADS, 0, stream>>>(x, W, nullptr, nullptr, out);
    }
}

// Round 13
// 47.735 us; speedup vs baseline: 1.3088x; 1.3088x over previous
//
#include <hip/hip_runtime.h>

#define NEG_SLOPE 0.2f
#define EPS 1e-6f

// x: [B=4, C=64, V=3, N=32768] f32, W: [64,64] f32, out like x
// d[o,v,n] = sum_i W[o,i]*x[i,v,n]; out = dot>=0 ? x : x - 0.8*(dot/(dnsq+eps))*d
// bf16 MFMA (A=W frag, B=x frag), hi/lo 3-product split.
// R8 skeleton (best: 43.6us) + NONTEMPORAL epilogue stores: the 100MB output
// stream was evicting x from Infinity Cache (FETCH 49MB/dispatch for an
// L3-resident input). nt stores keep x resident -> fetch ~0.

#define C_CH 64
#define V_DIM 3
#define N_FULL 32768
#define NT 64
#define THREADS 512

typedef __attribute__((ext_vector_type(8))) short bf16x8;
typedef __attribute__((ext_vector_type(4))) float f32x4;

__device__ __forceinline__ ushort f2bf(float f) {
    union { float f; unsigned u; } v; v.f = f;
    unsigned r = v.u + 0x7FFFu + ((v.u >> 16) & 1u);  // RNE
    return (ushort)(r >> 16);
}
__device__ __forceinline__ float bf2f(ushort s) {
    union { unsigned u; float f; } v; v.u = ((unsigned)s) << 16; return v.f;
}
// pack f32 -> (hi bf16 | lo bf16) in 4 VALU: round-half-up hi, truncated lo
__device__ __forceinline__ unsigned pack_hl(float x) {
    union { float f; unsigned u; } a; a.f = x;
    unsigned t0 = a.u + 0x8000u;
    union { unsigned u; float f; } hb; hb.u = t0 & 0xffff0000u;
    union { float f; unsigned u; } rb; rb.f = x - hb.f;
    return __builtin_amdgcn_perm(t0, rb.u, 0x07060302u);  // [t0.b3,t0.b2,rb.b3,rb.b2]
}
__device__ __forceinline__ float u2f(unsigned u) {
    union { unsigned u; float f; } v; v.u = u; return v.f;
}

// ---- pre-kernel: split W fp32 -> Whi/Wlo bf16 (8 KB each), RNE both
__global__ void w_split_kernel(const float* __restrict__ W,
                               ushort* __restrict__ whi, ushort* __restrict__ wlo) {
    int i = blockIdx.x * 256 + threadIdx.x;
    if (i < C_CH * C_CH) {
        float w = W[i];
        ushort h = f2bf(w);
        whi[i] = h;
        wlo[i] = f2bf(w - bf2f(h));
    }
}

// dword-col swizzle: XOR col bits 4-5 with row bits 3-4 -> all accesses <=2-way
__device__ __forceinline__ int swz(int row) { return ((row >> 3) & 3) << 4; }

template<bool USE_WS>
__global__ __launch_bounds__(THREADS, 6)
void vn_mfma64(const float* __restrict__ x,
               const float* __restrict__ Wf,
               const ushort* __restrict__ whi, const ushort* __restrict__ wlo,
               float* __restrict__ out) {
    // LDS row = v*64 + i, packed (hi<<16)|lo. 48 KB.
    __shared__ unsigned xs[V_DIM * C_CH][NT];

    const int t    = threadIdx.x;
    const int tile = blockIdx.x;
    const int b    = tile >> 9;            // 512 tiles per batch
    const int n0   = (tile & 511) << 6;    // *64

    const float* xb = x + (size_t)b * (C_CH * V_DIM * N_FULL) + n0;

    const int lane = t & 63;
    const int w    = t >> 6;   // 0..7
    const int wo   = w >> 2;   // o-half -> 32 channels
    const int wn   = w & 3;    // n-quarter -> 16 cols
    const int l4   = lane & 15;
    const int hi   = lane >> 4;

    // ---- A fragments (W): row o = wo*32+m*16+l4, k = kh*32+hi*8+j
    bf16x8 Ah[2][2], Al[2][2];
    if (USE_WS) {
        #pragma unroll
        for (int m = 0; m < 2; ++m)
            #pragma unroll
            for (int kh = 0; kh < 2; ++kh) {
                size_t off = (size_t)(wo * 32 + m * 16 + l4) * C_CH + kh * 32 + hi * 8;
                Ah[m][kh] = *(const bf16x8*)(whi + off);
                Al[m][kh] = *(const bf16x8*)(wlo + off);
            }
    } else {
        #pragma unroll
        for (int m = 0; m < 2; ++m)
            #pragma unroll
            for (int kh = 0; kh < 2; ++kh) {
                const float* wp = Wf + (size_t)(wo * 32 + m * 16 + l4) * C_CH + kh * 32 + hi * 8;
                float4 wa = *(const float4*)wp;
                float4 wb = *(const float4*)(wp + 4);
                float wf[8] = {wa.x, wa.y, wa.z, wa.w, wb.x, wb.y, wb.z, wb.w};
                bf16x8 h, l;
                #pragma unroll
                for (int j = 0; j < 8; ++j) {
                    ushort hb = f2bf(wf[j]);
                    h[j] = (short)hb;
                    l[j] = (short)f2bf(wf[j] - bf2f(hb));
                }
                Ah[m][kh] = h; Al[m][kh] = l;
            }
    }

    // ---- stage x tile: 192 global rows x 64 f32 -> packed LDS [v*64+i][n]
    // global row r = 3*i + v ; LDS row = v*64 + i ; 16 float4 per row
    #pragma unroll
    for (int it = 0; it < 6; ++it) {
        int idx = t + it * THREADS;      // 0..3071 float4-slots
        int r   = idx >> 4;              // global row 0..191
        int c4  = (idx & 15) << 2;       // dword col base
        int i   = (r * 171) >> 9;        // r / 3 (exact for r < 768)
        int v   = r - 3 * i;
        int rowp = v * 64 + i;
        float4 vf4 = *(const float4*)(xb + (size_t)r * N_FULL + c4);
        unsigned p[4] = {pack_hl(vf4.x), pack_hl(vf4.y),
                         pack_hl(vf4.z), pack_hl(vf4.w)};
        *(uint4*)&xs[rowp][c4 ^ swz(rowp)] = *(const uint4*)p;
    }
    __syncthreads();

    f32x4 acc[2][3];
    #pragma unroll
    for (int m = 0; m < 2; ++m)
        #pragma unroll
        for (int v = 0; v < 3; ++v)
            acc[m][v] = (f32x4){0.f, 0.f, 0.f, 0.f};

    // ---- MFMA: B-frag (x) rows = v*64+kh*32+hi*8+j -> (row>>3)&3 == hi
    const int acol = (wn * 16 + l4) ^ (hi << 4);  // const per thread
    #pragma unroll
    for (int v = 0; v < 3; ++v) {
        #pragma unroll
        for (int kh = 0; kh < 2; ++kh) {
            const int rowb = v * 64 + kh * 32 + hi * 8;
            unsigned p[8];
            #pragma unroll
            for (int j = 0; j < 8; ++j)
                p[j] = xs[rowb + j][acol];
            union { bf16x8 v8; unsigned d[4]; } BH, BL;
            #pragma unroll
            for (int q = 0; q < 4; ++q) {
                BH.d[q] = __builtin_amdgcn_perm(p[2 * q + 1], p[2 * q], 0x07060302u);
                BL.d[q] = __builtin_amdgcn_perm(p[2 * q + 1], p[2 * q], 0x05040100u);
            }
            #pragma unroll
            for (int m = 0; m < 2; ++m) {
                acc[m][v] = __builtin_amdgcn_mfma_f32_16x16x32_bf16(Ah[m][kh], BH.v8, acc[m][v], 0, 0, 0);
                acc[m][v] = __builtin_amdgcn_mfma_f32_16x16x32_bf16(Ah[m][kh], BL.v8, acc[m][v], 0, 0, 0);
                acc[m][v] = __builtin_amdgcn_mfma_f32_16x16x32_bf16(Al[m][kh], BH.v8, acc[m][v], 0, 0, 0);
            }
        }
    }

    // ---- epilogue: C/D col=l4 (n), row=hi*4+r (o within 16)
    // NONTEMPORAL coalesced stores: don't let the out-stream evict x from L3
    const int n = wn * 16 + l4;
    float* ob = out + (size_t)b * (C_CH * V_DIM * N_FULL) + n0 + n;
    #pragma unroll
    for (int m = 0; m < 2; ++m) {
        #pragma unroll
        for (int r = 0; r < 4; ++r) {
            const int o = wo * 32 + m * 16 + hi * 4 + r;
            // row = v*64+o -> (row>>3)&3 = (m*2 + (hi>>1)) & 3
            const int ecol = n ^ (((m * 2 + (hi >> 1)) & 3) << 4);
            float xv[3], dv[3];
            #pragma unroll
            for (int v = 0; v < 3; ++v) {
                unsigned p = xs[v * 64 + o][ecol];
                xv[v] = u2f(p & 0xffff0000u) + u2f(p << 16);
                dv[v] = acc[m][v][r];
            }
            float dot  = xv[0] * dv[0] + xv[1] * dv[1] + xv[2] * dv[2];
            float dnsq = dv[0] * dv[0] + dv[1] * dv[1] + dv[2] * dv[2];
            float f = (1.0f - NEG_SLOPE) * dot * __builtin_amdgcn_rcpf(dnsq + EPS);
            f = (dot >= 0.f) ? 0.f : f;
            float o0 = fmaf(-f, dv[0], xv[0]);
            float o1 = fmaf(-f, dv[1], xv[1]);
            float o2 = fmaf(-f, dv[2], xv[2]);
            float* op = ob + (size_t)o * (V_DIM * N_FULL);
            __builtin_nontemporal_store(o0, op + 0 * N_FULL);
            __builtin_nontemporal_store(o1, op + 1 * N_FULL);
            __builtin_nontemporal_store(o2, op + 2 * N_FULL);
        }
    }
}

extern "C" void kernel_launch(void* const* d_in, const int* in_sizes, int n_in,
                              void* d_out, int out_size, void* d_ws, size_t ws_size,
                              hipStream_t stream) {
    const float* x = (const float*)d_in[0];
    const float* W = (const float*)d_in[1];
    float* out = (float*)d_out;

    const int B = 4;
    const int blocks = B * (N_FULL / NT);  // 2048

    if (ws_size >= 2u * C_CH * C_CH * sizeof(ushort)) {
        ushort* whi = (ushort*)d_ws;
        ushort* wlo = whi + C_CH * C_CH;
        w_split_kernel<<<(C_CH * C_CH + 255) / 256, 256, 0, stream>>>(W, whi, wlo);
        vn_mfma64<true><<<blocks, THREADS, 0, stream>>>(x, W, whi, wlo, out);
    } else {
        vn_mfma64<false><<<blocks, THREADS, 0, stream>>>(x, W, nullptr, nullptr, out);
    }
}

// Round 14
// 42.758 us; speedup vs baseline: 1.4612x; 1.1164x over previous
//
#include <hip/hip_runtime.h>

#define NEG_SLOPE 0.2f
#define EPS 1e-6f

// x: [B=4, C=64, V=3, N=32768] f32, W: [64,64] f32, out like x
// d[o,v,n] = sum_i W[o,i]*x[i,v,n]; out = dot>=0 ? x : x - 0.8*(dot/(dnsq+eps))*d
// bf16 MFMA (A=W frag, B=x frag), hi/lo 3-product split.
// R8 skeleton, single-dispatch (W split in-kernel), launch_bounds(512,4) so the
// allocator keeps all 6 staging loads in flight (R10 lesson: bounds=6 forced
// VGPR=40 and serialized staging).

#define C_CH 64
#define V_DIM 3
#define N_FULL 32768
#define NT 64
#define THREADS 512

typedef __attribute__((ext_vector_type(8))) short bf16x8;
typedef __attribute__((ext_vector_type(4))) float f32x4;

__device__ __forceinline__ ushort f2bf(float f) {
    union { float f; unsigned u; } v; v.f = f;
    unsigned r = v.u + 0x7FFFu + ((v.u >> 16) & 1u);  // RNE
    return (ushort)(r >> 16);
}
__device__ __forceinline__ float bf2f(ushort s) {
    union { unsigned u; float f; } v; v.u = ((unsigned)s) << 16; return v.f;
}
// pack f32 -> (hi bf16 | lo bf16) in 4 VALU: round-half-up hi, truncated lo
__device__ __forceinline__ unsigned pack_hl(float x) {
    union { float f; unsigned u; } a; a.f = x;
    unsigned t0 = a.u + 0x8000u;
    union { unsigned u; float f; } hb; hb.u = t0 & 0xffff0000u;
    union { float f; unsigned u; } rb; rb.f = x - hb.f;
    return __builtin_amdgcn_perm(t0, rb.u, 0x07060302u);  // [t0.b3,t0.b2,rb.b3,rb.b2]
}
__device__ __forceinline__ float u2f(unsigned u) {
    union { unsigned u; float f; } v; v.u = u; return v.f;
}

// dword-col swizzle: XOR col bits 4-5 with row bits 3-4 -> all accesses <=2-way
__device__ __forceinline__ int swz(int row) { return ((row >> 3) & 3) << 4; }

__global__ __launch_bounds__(THREADS, 4)
void vn_mfma64(const float* __restrict__ x,
               const float* __restrict__ Wf,
               float* __restrict__ out) {
    // LDS row = v*64 + i, packed (hi<<16)|lo. 48 KB.
    __shared__ unsigned xs[V_DIM * C_CH][NT];

    const int t    = threadIdx.x;
    const int tile = blockIdx.x;
    const int b    = tile >> 9;            // 512 tiles per batch
    const int n0   = (tile & 511) << 6;    // *64

    const float* xb = x + (size_t)b * (C_CH * V_DIM * N_FULL) + n0;

    const int lane = t & 63;
    const int w    = t >> 6;   // 0..7
    const int wo   = w >> 2;   // o-half -> 32 channels
    const int wn   = w & 3;    // n-quarter -> 16 cols
    const int l4   = lane & 15;
    const int hi   = lane >> 4;

    // ---- issue ALL 6 x-tile loads first (stay in flight; bounds=4 gives regs)
    float4 xr[6];
    #pragma unroll
    for (int it = 0; it < 6; ++it) {
        int idx = t + it * THREADS;      // 0..3071 float4-slots
        int r   = idx >> 4;              // global row 0..191
        int c4  = (idx & 15) << 2;       // dword col base
        xr[it] = *(const float4*)(xb + (size_t)r * N_FULL + c4);
    }

    // ---- A fragments (W) computed in-kernel under the x-load shadow:
    // row o = wo*32+m*16+l4, k = kh*32+hi*8+j; hi/lo RNE split
    bf16x8 Ah[2][2], Al[2][2];
    #pragma unroll
    for (int m = 0; m < 2; ++m)
        #pragma unroll
        for (int kh = 0; kh < 2; ++kh) {
            const float* wp = Wf + (size_t)(wo * 32 + m * 16 + l4) * C_CH + kh * 32 + hi * 8;
            float4 wa = *(const float4*)wp;
            float4 wb = *(const float4*)(wp + 4);
            float wf[8] = {wa.x, wa.y, wa.z, wa.w, wb.x, wb.y, wb.z, wb.w};
            bf16x8 h, l;
            #pragma unroll
            for (int j = 0; j < 8; ++j) {
                ushort hb = f2bf(wf[j]);
                h[j] = (short)hb;
                l[j] = (short)f2bf(wf[j] - bf2f(hb));
            }
            Ah[m][kh] = h; Al[m][kh] = l;
        }

    // ---- pack staged x -> LDS
    #pragma unroll
    for (int it = 0; it < 6; ++it) {
        int idx = t + it * THREADS;
        int r   = idx >> 4;
        int c4  = (idx & 15) << 2;
        int i   = (r * 171) >> 9;        // r / 3 (exact for r < 768)
        int v   = r - 3 * i;
        int rowp = v * 64 + i;
        unsigned p[4] = {pack_hl(xr[it].x), pack_hl(xr[it].y),
                         pack_hl(xr[it].z), pack_hl(xr[it].w)};
        *(uint4*)&xs[rowp][c4 ^ swz(rowp)] = *(const uint4*)p;
    }
    __syncthreads();

    f32x4 acc[2][3];
    #pragma unroll
    for (int m = 0; m < 2; ++m)
        #pragma unroll
        for (int v = 0; v < 3; ++v)
            acc[m][v] = (f32x4){0.f, 0.f, 0.f, 0.f};

    // ---- MFMA: B-frag (x) rows = v*64+kh*32+hi*8+j -> (row>>3)&3 == hi
    const int acol = (wn * 16 + l4) ^ (hi << 4);  // const per thread
    #pragma unroll
    for (int v = 0; v < 3; ++v) {
        #pragma unroll
        for (int kh = 0; kh < 2; ++kh) {
            const int rowb = v * 64 + kh * 32 + hi * 8;
            unsigned p[8];
            #pragma unroll
            for (int j = 0; j < 8; ++j)
                p[j] = xs[rowb + j][acol];
            union { bf16x8 v8; unsigned d[4]; } BH, BL;
            #pragma unroll
            for (int q = 0; q < 4; ++q) {
                BH.d[q] = __builtin_amdgcn_perm(p[2 * q + 1], p[2 * q], 0x07060302u);
                BL.d[q] = __builtin_amdgcn_perm(p[2 * q + 1], p[2 * q], 0x05040100u);
            }
            #pragma unroll
            for (int m = 0; m < 2; ++m) {
                acc[m][v] = __builtin_amdgcn_mfma_f32_16x16x32_bf16(Ah[m][kh], BH.v8, acc[m][v], 0, 0, 0);
                acc[m][v] = __builtin_amdgcn_mfma_f32_16x16x32_bf16(Ah[m][kh], BL.v8, acc[m][v], 0, 0, 0);
                acc[m][v] = __builtin_amdgcn_mfma_f32_16x16x32_bf16(Al[m][kh], BH.v8, acc[m][v], 0, 0, 0);
            }
        }
    }

    // ---- epilogue: C/D col=l4 (n), row=hi*4+r (o within 16); coalesced stores
    const int n = wn * 16 + l4;
    float* ob = out + (size_t)b * (C_CH * V_DIM * N_FULL) + n0 + n;
    #pragma unroll
    for (int m = 0; m < 2; ++m) {
        #pragma unroll
        for (int r = 0; r < 4; ++r) {
            const int o = wo * 32 + m * 16 + hi * 4 + r;
            // row = v*64+o -> (row>>3)&3 = (m*2 + (hi>>1)) & 3
            const int ecol = n ^ (((m * 2 + (hi >> 1)) & 3) << 4);
            float xv[3], dv[3];
            #pragma unroll
            for (int v = 0; v < 3; ++v) {
                unsigned p = xs[v * 64 + o][ecol];
                xv[v] = u2f(p & 0xffff0000u) + u2f(p << 16);
                dv[v] = acc[m][v][r];
            }
            float dot  = xv[0] * dv[0] + xv[1] * dv[1] + xv[2] * dv[2];
            float dnsq = dv[0] * dv[0] + dv[1] * dv[1] + dv[2] * dv[2];
            float f = (1.0f - NEG_SLOPE) * dot * __builtin_amdgcn_rcpf(dnsq + EPS);
            f = (dot >= 0.f) ? 0.f : f;
            float o0 = fmaf(-f, dv[0], xv[0]);
            float o1 = fmaf(-f, dv[1], xv[1]);
            float o2 = fmaf(-f, dv[2], xv[2]);
            float* op = ob + (size_t)o * (V_DIM * N_FULL);
            op[0 * N_FULL] = o0;
            op[1 * N_FULL] = o1;
            op[2 * N_FULL] = o2;
        }
    }
}

extern "C" void kernel_launch(void* const* d_in, const int* in_sizes, int n_in,
                              void* d_out, int out_size, void* d_ws, size_t ws_size,
                              hipStream_t stream) {
    const float* x = (const float*)d_in[0];
    const float* W = (const float*)d_in[1];
    float* out = (float*)d_out;

    const int B = 4;
    const int blocks = B * (N_FULL / NT);  // 2048
    vn_mfma64<<<blocks, THREADS, 0, stream>>>(x, W, out);
}

// Round 15
// 38.688 us; speedup vs baseline: 1.6149x; 1.1052x over previous
//
#include <hip/hip_runtime.h>

#define NEG_SLOPE 0.2f
#define EPS 1e-6f

// x: [B=4, C=64, V=3, N=32768] f32, W: [64,64] f32, out like x
// d[o,v,n] = sum_i W[o,i]*x[i,v,n]; out = dot>=0 ? x : x - 0.8*(dot/(dnsq+eps))*d
// bf16 MFMA (A=W frag, B=x frag), hi/lo 3-product split.
// Cross-tile 2-phase pipeline: TPB=4 tiles/block, LDS double-buffer (2x24KB),
// next tile's global loads issued before current tile's compute, one barrier
// per tile. NT=32, 256 threads; W split in-kernel once per block.

#define C_CH 64
#define V_DIM 3
#define N_FULL 32768
#define NT 32
#define THREADS 256
#define TPB 4

typedef __attribute__((ext_vector_type(8))) short bf16x8;
typedef __attribute__((ext_vector_type(4))) float f32x4;

__device__ __forceinline__ ushort f2bf(float f) {
    union { float f; unsigned u; } v; v.f = f;
    unsigned r = v.u + 0x7FFFu + ((v.u >> 16) & 1u);  // RNE
    return (ushort)(r >> 16);
}
__device__ __forceinline__ float bf2f(ushort s) {
    union { unsigned u; float f; } v; v.u = ((unsigned)s) << 16; return v.f;
}
// pack f32 -> (hi bf16 | lo bf16) in 4 VALU: round-half-up hi, truncated lo
__device__ __forceinline__ unsigned pack_hl(float x) {
    union { float f; unsigned u; } a; a.f = x;
    unsigned t0 = a.u + 0x8000u;
    union { unsigned u; float f; } hb; hb.u = t0 & 0xffff0000u;
    union { float f; unsigned u; } rb; rb.f = x - hb.f;
    return __builtin_amdgcn_perm(t0, rb.u, 0x07060302u);  // [t0.b3,t0.b2,rb.b3,rb.b2]
}
__device__ __forceinline__ float u2f(unsigned u) {
    union { unsigned u; float f; } v; v.u = u; return v.f;
}

// dword-col swizzle for NT=32: XOR col bit 4 with row bit 3 -> <=2-way everywhere
__device__ __forceinline__ int swz(int row) { return ((row >> 3) & 1) << 4; }

__global__ __launch_bounds__(THREADS, 3)
void vn_pipe(const float* __restrict__ x,
             const float* __restrict__ Wf,
             float* __restrict__ out) {
    // double buffer: LDS row = v*64 + i, packed (hi<<16)|lo. 2 x 24 KB.
    __shared__ unsigned xs[2][V_DIM * C_CH][NT];

    const int t     = threadIdx.x;
    const int tile0 = blockIdx.x * TPB;          // 4096 tiles total, 1024 blocks
    const int b     = tile0 >> 10;               // batch (blocks never straddle)
    const float* xbase = x   + (size_t)b * (C_CH * V_DIM * N_FULL);
    float*       obase = out + (size_t)b * (C_CH * V_DIM * N_FULL);

    const int lane = t & 63;
    const int w    = t >> 6;   // 0..3
    const int wo   = w >> 1;   // o-half -> 32 channels
    const int wn   = w & 1;    // n-half -> 16 cols
    const int l4   = lane & 15;
    const int hi   = lane >> 4;

    // staging geometry (per thread, 6 float4 slots)
    // idx = t + it*256 -> global row r = idx>>3 (0..191), chunk c4 = (idx&7)*4
    // LDS row = v*64+i (r = 3i+v)

    // ---- prologue: issue tile0 loads
    float4 xr[6];
    {
        const float* xb = xbase + ((tile0 & 1023) << 5);
        #pragma unroll
        for (int it = 0; it < 6; ++it) {
            int idx = t + it * THREADS;
            xr[it] = *(const float4*)(xb + (size_t)(idx >> 3) * N_FULL + ((idx & 7) << 2));
        }
    }

    // ---- A fragments (W) under the load shadow: row o = wo*32+m*16+l4,
    // k = kh*32+hi*8+j; RNE hi/lo split
    bf16x8 Ah[2][2], Al[2][2];
    #pragma unroll
    for (int m = 0; m < 2; ++m)
        #pragma unroll
        for (int kh = 0; kh < 2; ++kh) {
            const float* wp = Wf + (size_t)(wo * 32 + m * 16 + l4) * C_CH + kh * 32 + hi * 8;
            float4 wa = *(const float4*)wp;
            float4 wb = *(const float4*)(wp + 4);
            float wf[8] = {wa.x, wa.y, wa.z, wa.w, wb.x, wb.y, wb.z, wb.w};
            bf16x8 h, l;
            #pragma unroll
            for (int j = 0; j < 8; ++j) {
                ushort hb = f2bf(wf[j]);
                h[j] = (short)hb;
                l[j] = (short)f2bf(wf[j] - bf2f(hb));
            }
            Ah[m][kh] = h; Al[m][kh] = l;
        }

    // ---- pack tile0 -> buf0
    #pragma unroll
    for (int it = 0; it < 6; ++it) {
        int idx = t + it * THREADS;
        int r   = idx >> 3;
        int c4  = (idx & 7) << 2;
        int i   = (r * 171) >> 9;        // r/3 (exact for r<768)
        int v   = r - 3 * i;
        int rowp = v * 64 + i;
        unsigned p[4] = {pack_hl(xr[it].x), pack_hl(xr[it].y),
                         pack_hl(xr[it].z), pack_hl(xr[it].w)};
        *(uint4*)&xs[0][rowp][c4 ^ swz(rowp)] = *(const uint4*)p;
    }
    __syncthreads();

    const int acol = (wn * 16 + l4) ^ ((hi & 1) << 4);  // B-frag col, const
    const int n    = wn * 16 + l4;
    const int ecol = n ^ ((hi >> 1) << 4);              // epilogue col, const

    #pragma unroll
    for (int tt = 0; tt < TPB; ++tt) {
        const int cur = tt & 1;
        const int n0c = ((tile0 + tt) & 1023) << 5;

        // ---- issue NEXT tile's loads first (fly under compute below)
        if (tt + 1 < TPB) {
            const float* xb = xbase + (((tile0 + tt + 1) & 1023) << 5);
            #pragma unroll
            for (int it = 0; it < 6; ++it) {
                int idx = t + it * THREADS;
                xr[it] = *(const float4*)(xb + (size_t)(idx >> 3) * N_FULL + ((idx & 7) << 2));
            }
        }

        // ---- compute tile tt from xs[cur]
        f32x4 acc[2][3];
        #pragma unroll
        for (int m = 0; m < 2; ++m)
            #pragma unroll
            for (int v = 0; v < 3; ++v)
                acc[m][v] = (f32x4){0.f, 0.f, 0.f, 0.f};

        #pragma unroll
        for (int v = 0; v < 3; ++v) {
            #pragma unroll
            for (int kh = 0; kh < 2; ++kh) {
                const int rowb = v * 64 + kh * 32 + hi * 8;
                unsigned p[8];
                #pragma unroll
                for (int j = 0; j < 8; ++j)
                    p[j] = xs[cur][rowb + j][acol];
                union { bf16x8 v8; unsigned d[4]; } BH, BL;
                #pragma unroll
                for (int q = 0; q < 4; ++q) {
                    BH.d[q] = __builtin_amdgcn_perm(p[2 * q + 1], p[2 * q], 0x07060302u);
                    BL.d[q] = __builtin_amdgcn_perm(p[2 * q + 1], p[2 * q], 0x05040100u);
                }
                #pragma unroll
                for (int m = 0; m < 2; ++m) {
                    acc[m][v] = __builtin_amdgcn_mfma_f32_16x16x32_bf16(Ah[m][kh], BH.v8, acc[m][v], 0, 0, 0);
                    acc[m][v] = __builtin_amdgcn_mfma_f32_16x16x32_bf16(Ah[m][kh], BL.v8, acc[m][v], 0, 0, 0);
                    acc[m][v] = __builtin_amdgcn_mfma_f32_16x16x32_bf16(Al[m][kh], BH.v8, acc[m][v], 0, 0, 0);
                }
            }
        }

        // ---- epilogue for tile tt: C/D col=l4 (n), row=hi*4+rr
        float* ob = obase + n0c + n;
        #pragma unroll
        for (int m = 0; m < 2; ++m) {
            #pragma unroll
            for (int rr = 0; rr < 4; ++rr) {
                const int o = wo * 32 + m * 16 + hi * 4 + rr;
                float xv[3], dv[3];
                #pragma unroll
                for (int v = 0; v < 3; ++v) {
                    unsigned p = xs[cur][v * 64 + o][ecol];
                    xv[v] = u2f(p & 0xffff0000u) + u2f(p << 16);
                    dv[v] = acc[m][v][rr];
                }
                float dot  = xv[0] * dv[0] + xv[1] * dv[1] + xv[2] * dv[2];
                float dnsq = dv[0] * dv[0] + dv[1] * dv[1] + dv[2] * dv[2];
                float f = (1.0f - NEG_SLOPE) * dot * __builtin_amdgcn_rcpf(dnsq + EPS);
                f = (dot >= 0.f) ? 0.f : f;
                float o0 = fmaf(-f, dv[0], xv[0]);
                float o1 = fmaf(-f, dv[1], xv[1]);
                float o2 = fmaf(-f, dv[2], xv[2]);
                float* op = ob + (size_t)o * (V_DIM * N_FULL);
                op[0 * N_FULL] = o0;
                op[1 * N_FULL] = o1;
                op[2 * N_FULL] = o2;
            }
        }

        // ---- pack NEXT tile into the other buffer (prev reads of it ended
        // before last barrier), then fence for its consumers
        if (tt + 1 < TPB) {
            #pragma unroll
            for (int it = 0; it < 6; ++it) {
                int idx = t + it * THREADS;
                int r   = idx >> 3;
                int c4  = (idx & 7) << 2;
                int i   = (r * 171) >> 9;
                int v   = r - 3 * i;
                int rowp = v * 64 + i;
                unsigned p[4] = {pack_hl(xr[it].x), pack_hl(xr[it].y),
                                 pack_hl(xr[it].z), pack_hl(xr[it].w)};
                *(uint4*)&xs[cur ^ 1][rowp][c4 ^ swz(rowp)] = *(const uint4*)p;
            }
        }
        __syncthreads();
    }
}

extern "C" void kernel_launch(void* const* d_in, const int* in_sizes, int n_in,
                              void* d_out, int out_size, void* d_ws, size_t ws_size,
                              hipStream_t stream) {
    const float* x = (const float*)d_in[0];
    const float* W = (const float*)d_in[1];
    float* out = (float*)d_out;

    const int B = 4;
    const int blocks = B * (N_FULL / NT) / TPB;  // 1024
    vn_pipe<<<blocks, THREADS, 0, stream>>>(x, W, out);
}